// Round 7
// baseline (1767.410 us; speedup 1.0000x reference)
//
#include <hip/hip_runtime.h>

// ---------------------------------------------------------------------------
// NeuralSplineCouplingLayer fused kernel (MI355X / gfx950) — round 7
// History: R4 713us (row-major A, conflicts 6.3e7, fit in 64 VGPR).
//          R5 920us / R6 1104us: restructures spilled at the 64-VGPR cap
//          forced by __launch_bounds__(1024,4) -> 0.6-1.4GB scratch traffic.
// LDS=147KB already limits to ONE 1024-thr block/CU (4 waves/SIMD), so up to
// 128 VGPR is free. Fixes:
//   1) __launch_bounds__(1024) — cap 128, no spills
//   2) gemm12 N-tiles processed sequentially (unroll 1): ~50 live regs peak
//   3) keep frag-linear A (conflict-free), recompute-exp spline
// ---------------------------------------------------------------------------

typedef _Float16 v8h __attribute__((ext_vector_type(8)));
typedef float v4f __attribute__((ext_vector_type(4)));

#define ROWS_PER_BLOCK 32
#define NBLOCKS 2048
#define NWAVES 16

// LDS layout (bytes). A-planes fragment-linear: plane[mt][ks][lane][8] fp16.
//   sInpHi [0,      8192)   2 x 4  x 64 x 8
//   sInpLo [8192,  16384)
//   sH1Hi  [16384, 49152)   2 x 16 x 64 x 8
//   sH1Lo  [49152, 81920)
//   sH2Hi  [81920, 114688)
//   sH2Lo  [114688,147456)
//   sRaw   [0,     49664)   32 x 388 f32 — overlays inp+h1 (dead in phase 3)
#define SMEM_BYTES 147456
#define S_INPLO 8192
#define S_H1HI  16384
#define S_H1LO  49152
#define S_H2HI  81920
#define S_H2LO  114688
#define RAW_STRIDE 388

#define LO_SCALE 2048.f
#define LO_INV   (1.f / 2048.f)

__device__ __forceinline__ void split2(float x, _Float16& hi, _Float16& lo) {
    _Float16 h = (_Float16)x;
    hi = h;
    lo = (_Float16)((x - (float)h) * LO_SCALE);
}
__device__ __forceinline__ float silu_f(float v) {
    return v / (1.f + __expf(-v));
}
__device__ __forceinline__ float softplus_f(float v) {
    return v > 15.f ? v : __logf(1.f + __expf(v));
}

// --- prep: W (K x N) f32 -> fragment-contiguous fp16 hi/lo -----------------
// Bfrag[j][ks][lane][e]: col n = j*16+(lane&15), k = ks*32+((lane>>4)<<3)+e.
__global__ void nscl_prep_frag(const float* __restrict__ src,
                               _Float16* __restrict__ hi, _Float16* __restrict__ lo,
                               int K, int N) {
    int idx = blockIdx.x * blockDim.x + threadIdx.x;
    if (idx >= N * K) return;
    const int e    = idx & 7;
    const int lane = (idx >> 3) & 63;
    const int rem  = idx >> 9;
    const int KS   = K >> 5;
    const int ks   = rem % KS;
    const int j    = rem / KS;
    const int n = j * 16 + (lane & 15);
    const int k = ks * 32 + ((lane >> 4) << 3) + e;
    split2(src[k * N + n], hi[idx], lo[idx]);
}

// --- GEMM1/2: wave owns 2 N-tiles, processed SEQUENTIALLY (low reg press) --
template<int KS>
__device__ __forceinline__ void gemm12(const _Float16* __restrict__ sAhi,
                                       const _Float16* __restrict__ sAlo,
                                       const _Float16* __restrict__ Bhi,
                                       const _Float16* __restrict__ Blo,
                                       const float* __restrict__ bias,
                                       _Float16* __restrict__ sOutHi,
                                       _Float16* __restrict__ sOutLo,
                                       int wave, int lane) {
    const int r2b = (lane >> 4) * 4;
    #pragma unroll 1
    for (int jj = 0; jj < 2; ++jj) {
        const int j = wave * 2 + jj;
        v4f m0 = {0,0,0,0}, m1 = {0,0,0,0};
        v4f c0 = {0,0,0,0}, c1 = {0,0,0,0};
        #pragma unroll
        for (int ks = 0; ks < KS; ++ks) {
            const int ab = (ks * 64 + lane) * 8;
            v8h a0h = *(const v8h*)(sAhi + ab);
            v8h a0l = *(const v8h*)(sAlo + ab);
            v8h a1h = *(const v8h*)(sAhi + KS * 512 + ab);
            v8h a1l = *(const v8h*)(sAlo + KS * 512 + ab);
            const int bo = ((j * KS + ks) * 64 + lane) * 8;
            v8h bh = *(const v8h*)(Bhi + bo);
            v8h bl = *(const v8h*)(Blo + bo);
            m0 = __builtin_amdgcn_mfma_f32_16x16x32_f16(a0h, bh, m0, 0, 0, 0);
            m1 = __builtin_amdgcn_mfma_f32_16x16x32_f16(a1h, bh, m1, 0, 0, 0);
            c0 = __builtin_amdgcn_mfma_f32_16x16x32_f16(a0h, bl, c0, 0, 0, 0);
            c0 = __builtin_amdgcn_mfma_f32_16x16x32_f16(a0l, bh, c0, 0, 0, 0);
            c1 = __builtin_amdgcn_mfma_f32_16x16x32_f16(a1h, bl, c1, 0, 0, 0);
            c1 = __builtin_amdgcn_mfma_f32_16x16x32_f16(a1l, bh, c1, 0, 0, 0);
        }
        // epilogue -> fragment layout (out K-dim = 512, KSout = 16)
        const int C   = j * 16 + (lane & 15);
        const int ks2 = C >> 5, g2 = (C >> 3) & 3, e2 = C & 7;
        const float bv = bias[C];
        #pragma unroll
        for (int rr = 0; rr < 4; ++rr) {
            float v0 = silu_f(m0[rr] + c0[rr] * LO_INV + bv);
            float v1 = silu_f(m1[rr] + c1[rr] * LO_INV + bv);
            const int off0 = ((0 * 16 + ks2) * 64 + g2 * 16 + r2b + rr) * 8 + e2;
            const int off1 = ((1 * 16 + ks2) * 64 + g2 * 16 + r2b + rr) * 8 + e2;
            split2(v0, sOutHi[off0], sOutLo[off0]);
            split2(v1, sOutHi[off1], sOutLo[off1]);
        }
    }
}

// --- GEMM3 chunk: 24 tiles from t0, one tile per iter, named accs ----------
__device__ __forceinline__ void gemm3(const _Float16* __restrict__ sAhi,
                                      const _Float16* __restrict__ sAlo,
                                      const _Float16* __restrict__ Bhi,
                                      const _Float16* __restrict__ Blo,
                                      const float* __restrict__ b3,
                                      float* __restrict__ sRaw,
                                      int t0, int wave, int lane) {
    #pragma unroll 1
    for (int tt = wave; tt < 24; tt += NWAVES) {
        const int jt = t0 + tt;
        v4f m0 = {0,0,0,0}, m1 = {0,0,0,0};
        v4f cc0 = {0,0,0,0}, cc1 = {0,0,0,0};
        #pragma unroll
        for (int ks = 0; ks < 16; ++ks) {
            const int ab = (ks * 64 + lane) * 8;
            v8h a0h = *(const v8h*)(sAhi + ab);
            v8h a0l = *(const v8h*)(sAlo + ab);
            v8h a1h = *(const v8h*)(sAhi + 8192 + ab);
            v8h a1l = *(const v8h*)(sAlo + 8192 + ab);
            const int bo = ((jt * 16 + ks) * 64 + lane) * 8;
            v8h bh = *(const v8h*)(Bhi + bo);
            v8h bl = *(const v8h*)(Blo + bo);
            m0  = __builtin_amdgcn_mfma_f32_16x16x32_f16(a0h, bh, m0, 0, 0, 0);
            m1  = __builtin_amdgcn_mfma_f32_16x16x32_f16(a1h, bh, m1, 0, 0, 0);
            cc0 = __builtin_amdgcn_mfma_f32_16x16x32_f16(a0h, bl, cc0, 0, 0, 0);
            cc0 = __builtin_amdgcn_mfma_f32_16x16x32_f16(a0l, bh, cc0, 0, 0, 0);
            cc1 = __builtin_amdgcn_mfma_f32_16x16x32_f16(a1h, bl, cc1, 0, 0, 0);
            cc1 = __builtin_amdgcn_mfma_f32_16x16x32_f16(a1l, bh, cc1, 0, 0, 0);
        }
        const int lr   = lane & 15;
        const int lcol = tt * 16 + lr;
        const float bv = b3[jt * 16 + lr];
        const int r2b  = (lane >> 4) * 4;
        #pragma unroll
        for (int rr = 0; rr < 4; ++rr) {
            sRaw[(r2b + rr) * RAW_STRIDE + lcol]      = m0[rr] + cc0[rr] * LO_INV + bv;
            sRaw[(16 + r2b + rr) * RAW_STRIDE + lcol] = m1[rr] + cc1[rr] * LO_INV + bv;
        }
    }
}

__global__ __launch_bounds__(1024)
void nscl_fused(const float* __restrict__ xp, const float* __restrict__ ctxp,
                const float* __restrict__ b1, const float* __restrict__ b2,
                const float* __restrict__ b3,
                const _Float16* __restrict__ W1Thi, const _Float16* __restrict__ W1Tlo,
                const _Float16* __restrict__ W2Thi, const _Float16* __restrict__ W2Tlo,
                const _Float16* __restrict__ W3Thi, const _Float16* __restrict__ W3Tlo,
                float* __restrict__ outY, float* __restrict__ outLD) {
    __shared__ __align__(16) char smem[SMEM_BYTES];
    _Float16* sInpHi = (_Float16*)smem;
    _Float16* sInpLo = (_Float16*)(smem + S_INPLO);
    _Float16* sH1Hi  = (_Float16*)(smem + S_H1HI);
    _Float16* sH1Lo  = (_Float16*)(smem + S_H1LO);
    _Float16* sH2Hi  = (_Float16*)(smem + S_H2HI);
    _Float16* sH2Lo  = (_Float16*)(smem + S_H2LO);
    float*    sRaw   = (float*)smem;               // overlay (phase 3)

    const int tid  = threadIdx.x;
    const int lane = tid & 63;
    const int wave = tid >> 6;
    const int row0 = blockIdx.x * ROWS_PER_BLOCK;

    // ---- stage masked input directly into fragment layout (array-free) ----
    if (tid < 512) {
        const int mt = tid >> 8;
        const int l  = tid & 63;
        const int row = mt * 16 + (l & 15);
        const int c0  = ((tid >> 6) & 3) * 32 + ((l >> 4) << 3);
        const int g   = row0 + row;
        v8h hi8, lo8;
        #pragma unroll
        for (int e = 0; e < 8; ++e) {
            float v;
            if (c0 < 64) v = ((c0 + e) & 1) ? 0.f : xp[g * 64 + c0 + e];
            else         v = ctxp[g * 64 + c0 - 64 + e];
            _Float16 h = (_Float16)v;
            hi8[e] = h;
            lo8[e] = (_Float16)((v - (float)h) * LO_SCALE);
        }
        *(v8h*)(sInpHi + tid * 8) = hi8;
        *(v8h*)(sInpLo + tid * 8) = lo8;
    }
    __syncthreads();

    gemm12<4>(sInpHi, sInpLo, W1Thi, W1Tlo, b1, sH1Hi, sH1Lo, wave, lane);
    __syncthreads();
    gemm12<16>(sH1Hi, sH1Lo, W2Thi, W2Tlo, b2, sH2Hi, sH2Lo, wave, lane);
    __syncthreads();

    // ---- GEMM3 + spline, 4 chunks of 8 transforms --------------------------
    const float TB = 5.0f;
    float ldacc = 0.f;
    const int r  = (tid < 256) ? (tid >> 3) : 0;
    const int tl = tid & 7;

    #pragma unroll 1
    for (int ch = 0; ch < 4; ++ch) {
        const int t0 = (ch * 47) >> 1;           // 0, 23, 47, 70
        gemm3(sH2Hi, sH2Lo, W3Thi, W3Tlo, b3, sRaw, t0, wave, lane);
        __syncthreads();

        if (tid < 256) {
            const int t = ch * 8 + tl;
            const int g = row0 + r;
            const float* pr = sRaw + r * RAW_STRIDE + ((ch & 1) ? 8 : 0) + tl * 47;

            // pass 1: maxes
            float mw = -1e30f, mh = -1e30f;
            #pragma unroll
            for (int i = 0; i < 16; ++i) {
                mw = fmaxf(mw, pr[i]);
                mh = fmaxf(mh, pr[16 + i]);
            }
            // pass 2: softmax sums
            float sw = 0.f, sh = 0.f;
            #pragma unroll
            for (int i = 0; i < 16; ++i) {
                sw += __expf(pr[i] - mw);
                sh += __expf(pr[16 + i] - mh);
            }
            const float scw = 10.f / sw;
            const float sch = 10.f / sh;

            const float xt = xp[g * 64 + 2 * t + 1];
            const float xc = fminf(fmaxf(xt, -TB + 1e-6f), TB - 1e-6f);

            // pass 3: bin count (sequential cumsum, recomputed exp)
            float cum = -TB; int cnt = 0;
            #pragma unroll
            for (int i = 0; i < 16; ++i) {
                cum += __expf(pr[i] - mw) * scw;
                cnt += (cum < xc) ? 1 : 0;
            }
            const int bin = cnt > 15 ? 15 : cnt;

            // pass 4: gather at bin (recomputed exp, predicated select)
            float w_k = 0.f, cw_k = 0.f, h_k = 0.f, ch_k = 0.f;
            float cw = -TB, chh = -TB;
            #pragma unroll
            for (int i = 0; i < 16; ++i) {
                const float wi = __expf(pr[i] - mw) * scw;
                const float hi = __expf(pr[16 + i] - mh) * sch;
                if (i == bin) { w_k = wi; cw_k = cw; h_k = hi; ch_k = chh; }
                cw += wi; chh += hi;
            }

            const float d_k  = (bin == 0)  ? 1.f : softplus_f(pr[31 + bin]);
            const float d_k1 = (bin == 15) ? 1.f : softplus_f(pr[32 + bin]);

            float xi = (xc - cw_k) / w_k;
            xi = fminf(fmaxf(xi, 0.f), 1.f);
            const float om = 1.f - xi;
            const float num = h_k * (d_k * xi * xi + 2.f * xi * om);
            const float den = d_k + (d_k1 + d_k - 2.f) * xi * om;
            const float yv  = ch_k + num / (den + 1e-8f);
            const float dv  = h_k * h_k * (d_k1 * xi * xi + 2.f * xi * om + d_k * om * om)
                              / (den * den * w_k + 1e-8f) + 1e-8f;

            float v = __logf(dv);
            v += __shfl_xor(v, 1);
            v += __shfl_xor(v, 2);
            v += __shfl_xor(v, 4);
            ldacc += v;

            outY[g * 64 + 2 * t]     = xp[g * 64 + 2 * t];
            outY[g * 64 + 2 * t + 1] = yv;
        }
        __syncthreads();
    }

    if (tid < 256 && tl == 0) outLD[row0 + r] = ldacc;
}

extern "C" void kernel_launch(void* const* d_in, const int* in_sizes, int n_in,
                              void* d_out, int out_size, void* d_ws, size_t ws_size,
                              hipStream_t stream) {
    (void)in_sizes; (void)n_in; (void)out_size; (void)ws_size;
    const float* x   = (const float*)d_in[0];
    const float* ctx = (const float*)d_in[1];
    const float* W1  = (const float*)d_in[2];
    const float* b1  = (const float*)d_in[3];
    const float* W2  = (const float*)d_in[4];
    const float* b2  = (const float*)d_in[5];
    const float* W3  = (const float*)d_in[6];
    const float* b3  = (const float*)d_in[7];

    _Float16* base = (_Float16*)d_ws;
    _Float16* W1Thi = base;                    // 512x128   = 65536
    _Float16* W1Tlo = base + 65536;
    _Float16* W2Thi = base + 131072;           // 512x512   = 262144
    _Float16* W2Tlo = base + 393216;
    _Float16* W3Thi = base + 655360;           // 1504x512  = 770048
    _Float16* W3Tlo = base + 1425408;

    nscl_prep_frag<<<(512 * 128 + 255) / 256, 256, 0, stream>>>(W1, W1Thi, W1Tlo, 128, 512);
    nscl_prep_frag<<<(512 * 512 + 255) / 256, 256, 0, stream>>>(W2, W2Thi, W2Tlo, 512, 512);
    nscl_prep_frag<<<(512 * 1504 + 255) / 256, 256, 0, stream>>>(W3, W3Thi, W3Tlo, 512, 1504);

    float* outY  = (float*)d_out;
    float* outLD = outY + 65536 * 64;

    nscl_fused<<<NBLOCKS, 1024, 0, stream>>>(x, ctx, b1, b2, b3,
                                             W1Thi, W1Tlo, W2Thi, W2Tlo, W3Thi, W3Tlo,
                                             outY, outLD);
}

// Round 9
// 1622.528 us; speedup vs baseline: 1.0893x; 1.0893x over previous
//
#include <hip/hip_runtime.h>

// ---------------------------------------------------------------------------
// NeuralSplineCouplingLayer fused kernel (MI355X / gfx950) — round 9
// R7 (dual-acc split-fp16) is numerically verified: absmax 0.0625. Its only
// problem: backend pins VGPR=64 for 1024-thread blocks -> K-loop spills ->
// up to 3.3GB scratch HBM traffic (R5-R7).
// R8's single-accumulator "fix" broke log_det (cross terms rounded at the
// main accumulator's ULP -> ~10x raw error -> bin flips). REVERTED.
// R9 = R7 source + amdgpu_waves_per_eu(4,4): LDS 147KB already caps at one
// block/CU (= 4 waves/EU), so pinning raises the VGPR budget to 128 for free.
// ---------------------------------------------------------------------------

typedef _Float16 v8h __attribute__((ext_vector_type(8)));
typedef float v4f __attribute__((ext_vector_type(4)));

#define ROWS_PER_BLOCK 32
#define NBLOCKS 2048
#define NWAVES 16

// LDS layout (bytes). A-planes fragment-linear: plane[mt][ks][lane][8] fp16.
//   sInpHi [0,      8192)   2 x 4  x 64 x 8
//   sInpLo [8192,  16384)
//   sH1Hi  [16384, 49152)   2 x 16 x 64 x 8
//   sH1Lo  [49152, 81920)
//   sH2Hi  [81920, 114688)
//   sH2Lo  [114688,147456)
//   sRaw   [0,     49664)   32 x 388 f32 — overlays inp+h1 (dead in phase 3)
#define SMEM_BYTES 147456
#define S_INPLO 8192
#define S_H1HI  16384
#define S_H1LO  49152
#define S_H2HI  81920
#define S_H2LO  114688
#define RAW_STRIDE 388

#define LO_SCALE 2048.f
#define LO_INV   (1.f / 2048.f)

__device__ __forceinline__ void split2(float x, _Float16& hi, _Float16& lo) {
    _Float16 h = (_Float16)x;
    hi = h;
    lo = (_Float16)((x - (float)h) * LO_SCALE);
}
__device__ __forceinline__ float silu_f(float v) {
    return v / (1.f + __expf(-v));
}
__device__ __forceinline__ float softplus_f(float v) {
    return v > 15.f ? v : __logf(1.f + __expf(v));
}

// --- prep: W (K x N) f32 -> fragment-contiguous fp16 hi/lo -----------------
// Bfrag[j][ks][lane][e]: col n = j*16+(lane&15), k = ks*32+((lane>>4)<<3)+e.
__global__ void nscl_prep_frag(const float* __restrict__ src,
                               _Float16* __restrict__ hi, _Float16* __restrict__ lo,
                               int K, int N) {
    int idx = blockIdx.x * blockDim.x + threadIdx.x;
    if (idx >= N * K) return;
    const int e    = idx & 7;
    const int lane = (idx >> 3) & 63;
    const int rem  = idx >> 9;
    const int KS   = K >> 5;
    const int ks   = rem % KS;
    const int j    = rem / KS;
    const int n = j * 16 + (lane & 15);
    const int k = ks * 32 + ((lane >> 4) << 3) + e;
    split2(src[k * N + n], hi[idx], lo[idx]);
}

// --- GEMM1/2: wave owns 2 N-tiles, processed SEQUENTIALLY (low reg press) --
template<int KS>
__device__ __forceinline__ void gemm12(const _Float16* __restrict__ sAhi,
                                       const _Float16* __restrict__ sAlo,
                                       const _Float16* __restrict__ Bhi,
                                       const _Float16* __restrict__ Blo,
                                       const float* __restrict__ bias,
                                       _Float16* __restrict__ sOutHi,
                                       _Float16* __restrict__ sOutLo,
                                       int wave, int lane) {
    const int r2b = (lane >> 4) * 4;
    #pragma unroll 1
    for (int jj = 0; jj < 2; ++jj) {
        const int j = wave * 2 + jj;
        v4f m0 = {0,0,0,0}, m1 = {0,0,0,0};
        v4f c0 = {0,0,0,0}, c1 = {0,0,0,0};
        #pragma unroll
        for (int ks = 0; ks < KS; ++ks) {
            const int ab = (ks * 64 + lane) * 8;
            v8h a0h = *(const v8h*)(sAhi + ab);
            v8h a0l = *(const v8h*)(sAlo + ab);
            v8h a1h = *(const v8h*)(sAhi + KS * 512 + ab);
            v8h a1l = *(const v8h*)(sAlo + KS * 512 + ab);
            const int bo = ((j * KS + ks) * 64 + lane) * 8;
            v8h bh = *(const v8h*)(Bhi + bo);
            v8h bl = *(const v8h*)(Blo + bo);
            m0 = __builtin_amdgcn_mfma_f32_16x16x32_f16(a0h, bh, m0, 0, 0, 0);
            m1 = __builtin_amdgcn_mfma_f32_16x16x32_f16(a1h, bh, m1, 0, 0, 0);
            c0 = __builtin_amdgcn_mfma_f32_16x16x32_f16(a0h, bl, c0, 0, 0, 0);
            c0 = __builtin_amdgcn_mfma_f32_16x16x32_f16(a0l, bh, c0, 0, 0, 0);
            c1 = __builtin_amdgcn_mfma_f32_16x16x32_f16(a1h, bl, c1, 0, 0, 0);
            c1 = __builtin_amdgcn_mfma_f32_16x16x32_f16(a1l, bh, c1, 0, 0, 0);
        }
        // epilogue -> fragment layout (out K-dim = 512, KSout = 16)
        const int C   = j * 16 + (lane & 15);
        const int ks2 = C >> 5, g2 = (C >> 3) & 3, e2 = C & 7;
        const float bv = bias[C];
        #pragma unroll
        for (int rr = 0; rr < 4; ++rr) {
            float v0 = silu_f(m0[rr] + c0[rr] * LO_INV + bv);
            float v1 = silu_f(m1[rr] + c1[rr] * LO_INV + bv);
            const int off0 = ((0 * 16 + ks2) * 64 + g2 * 16 + r2b + rr) * 8 + e2;
            const int off1 = ((1 * 16 + ks2) * 64 + g2 * 16 + r2b + rr) * 8 + e2;
            split2(v0, sOutHi[off0], sOutLo[off0]);
            split2(v1, sOutHi[off1], sOutLo[off1]);
        }
    }
}

// --- GEMM3 chunk: 24 tiles from t0, one tile per iter, named accs ----------
__device__ __forceinline__ void gemm3(const _Float16* __restrict__ sAhi,
                                      const _Float16* __restrict__ sAlo,
                                      const _Float16* __restrict__ Bhi,
                                      const _Float16* __restrict__ Blo,
                                      const float* __restrict__ b3,
                                      float* __restrict__ sRaw,
                                      int t0, int wave, int lane) {
    #pragma unroll 1
    for (int tt = wave; tt < 24; tt += NWAVES) {
        const int jt = t0 + tt;
        v4f m0 = {0,0,0,0}, m1 = {0,0,0,0};
        v4f cc0 = {0,0,0,0}, cc1 = {0,0,0,0};
        #pragma unroll
        for (int ks = 0; ks < 16; ++ks) {
            const int ab = (ks * 64 + lane) * 8;
            v8h a0h = *(const v8h*)(sAhi + ab);
            v8h a0l = *(const v8h*)(sAlo + ab);
            v8h a1h = *(const v8h*)(sAhi + 8192 + ab);
            v8h a1l = *(const v8h*)(sAlo + 8192 + ab);
            const int bo = ((jt * 16 + ks) * 64 + lane) * 8;
            v8h bh = *(const v8h*)(Bhi + bo);
            v8h bl = *(const v8h*)(Blo + bo);
            m0  = __builtin_amdgcn_mfma_f32_16x16x32_f16(a0h, bh, m0, 0, 0, 0);
            m1  = __builtin_amdgcn_mfma_f32_16x16x32_f16(a1h, bh, m1, 0, 0, 0);
            cc0 = __builtin_amdgcn_mfma_f32_16x16x32_f16(a0h, bl, cc0, 0, 0, 0);
            cc0 = __builtin_amdgcn_mfma_f32_16x16x32_f16(a0l, bh, cc0, 0, 0, 0);
            cc1 = __builtin_amdgcn_mfma_f32_16x16x32_f16(a1h, bl, cc1, 0, 0, 0);
            cc1 = __builtin_amdgcn_mfma_f32_16x16x32_f16(a1l, bh, cc1, 0, 0, 0);
        }
        const int lr   = lane & 15;
        const int lcol = tt * 16 + lr;
        const float bv = b3[jt * 16 + lr];
        const int r2b  = (lane >> 4) * 4;
        #pragma unroll
        for (int rr = 0; rr < 4; ++rr) {
            sRaw[(r2b + rr) * RAW_STRIDE + lcol]      = m0[rr] + cc0[rr] * LO_INV + bv;
            sRaw[(16 + r2b + rr) * RAW_STRIDE + lcol] = m1[rr] + cc1[rr] * LO_INV + bv;
        }
    }
}

__attribute__((amdgpu_waves_per_eu(4, 4)))
__global__ __launch_bounds__(1024)
void nscl_fused(const float* __restrict__ xp, const float* __restrict__ ctxp,
                const float* __restrict__ b1, const float* __restrict__ b2,
                const float* __restrict__ b3,
                const _Float16* __restrict__ W1Thi, const _Float16* __restrict__ W1Tlo,
                const _Float16* __restrict__ W2Thi, const _Float16* __restrict__ W2Tlo,
                const _Float16* __restrict__ W3Thi, const _Float16* __restrict__ W3Tlo,
                float* __restrict__ outY, float* __restrict__ outLD) {
    __shared__ __align__(16) char smem[SMEM_BYTES];
    _Float16* sInpHi = (_Float16*)smem;
    _Float16* sInpLo = (_Float16*)(smem + S_INPLO);
    _Float16* sH1Hi  = (_Float16*)(smem + S_H1HI);
    _Float16* sH1Lo  = (_Float16*)(smem + S_H1LO);
    _Float16* sH2Hi  = (_Float16*)(smem + S_H2HI);
    _Float16* sH2Lo  = (_Float16*)(smem + S_H2LO);
    float*    sRaw   = (float*)smem;               // overlay (phase 3)

    const int tid  = threadIdx.x;
    const int lane = tid & 63;
    const int wave = tid >> 6;
    const int row0 = blockIdx.x * ROWS_PER_BLOCK;

    // ---- stage masked input directly into fragment layout (array-free) ----
    if (tid < 512) {
        const int mt = tid >> 8;
        const int l  = tid & 63;
        const int row = mt * 16 + (l & 15);
        const int c0  = ((tid >> 6) & 3) * 32 + ((l >> 4) << 3);
        const int g   = row0 + row;
        v8h hi8, lo8;
        #pragma unroll
        for (int e = 0; e < 8; ++e) {
            float v;
            if (c0 < 64) v = ((c0 + e) & 1) ? 0.f : xp[g * 64 + c0 + e];
            else         v = ctxp[g * 64 + c0 - 64 + e];
            _Float16 h = (_Float16)v;
            hi8[e] = h;
            lo8[e] = (_Float16)((v - (float)h) * LO_SCALE);
        }
        *(v8h*)(sInpHi + tid * 8) = hi8;
        *(v8h*)(sInpLo + tid * 8) = lo8;
    }
    __syncthreads();

    gemm12<4>(sInpHi, sInpLo, W1Thi, W1Tlo, b1, sH1Hi, sH1Lo, wave, lane);
    __syncthreads();
    gemm12<16>(sH1Hi, sH1Lo, W2Thi, W2Tlo, b2, sH2Hi, sH2Lo, wave, lane);
    __syncthreads();

    // ---- GEMM3 + spline, 4 chunks of 8 transforms --------------------------
    const float TB = 5.0f;
    float ldacc = 0.f;
    const int r  = (tid < 256) ? (tid >> 3) : 0;
    const int tl = tid & 7;

    #pragma unroll 1
    for (int ch = 0; ch < 4; ++ch) {
        const int t0 = (ch * 47) >> 1;           // 0, 23, 47, 70
        gemm3(sH2Hi, sH2Lo, W3Thi, W3Tlo, b3, sRaw, t0, wave, lane);
        __syncthreads();

        if (tid < 256) {
            const int t = ch * 8 + tl;
            const int g = row0 + r;
            const float* pr = sRaw + r * RAW_STRIDE + ((ch & 1) ? 8 : 0) + tl * 47;

            // pass 1: maxes
            float mw = -1e30f, mh = -1e30f;
            #pragma unroll
            for (int i = 0; i < 16; ++i) {
                mw = fmaxf(mw, pr[i]);
                mh = fmaxf(mh, pr[16 + i]);
            }
            // pass 2: softmax sums
            float sw = 0.f, sh = 0.f;
            #pragma unroll
            for (int i = 0; i < 16; ++i) {
                sw += __expf(pr[i] - mw);
                sh += __expf(pr[16 + i] - mh);
            }
            const float scw = 10.f / sw;
            const float sch = 10.f / sh;

            const float xt = xp[g * 64 + 2 * t + 1];
            const float xc = fminf(fmaxf(xt, -TB + 1e-6f), TB - 1e-6f);

            // pass 3: bin count (sequential cumsum, recomputed exp)
            float cum = -TB; int cnt = 0;
            #pragma unroll
            for (int i = 0; i < 16; ++i) {
                cum += __expf(pr[i] - mw) * scw;
                cnt += (cum < xc) ? 1 : 0;
            }
            const int bin = cnt > 15 ? 15 : cnt;

            // pass 4: gather at bin (recomputed exp, predicated select)
            float w_k = 0.f, cw_k = 0.f, h_k = 0.f, ch_k = 0.f;
            float cw = -TB, chh = -TB;
            #pragma unroll
            for (int i = 0; i < 16; ++i) {
                const float wi = __expf(pr[i] - mw) * scw;
                const float hi = __expf(pr[16 + i] - mh) * sch;
                if (i == bin) { w_k = wi; cw_k = cw; h_k = hi; ch_k = chh; }
                cw += wi; chh += hi;
            }

            const float d_k  = (bin == 0)  ? 1.f : softplus_f(pr[31 + bin]);
            const float d_k1 = (bin == 15) ? 1.f : softplus_f(pr[32 + bin]);

            float xi = (xc - cw_k) / w_k;
            xi = fminf(fmaxf(xi, 0.f), 1.f);
            const float om = 1.f - xi;
            const float num = h_k * (d_k * xi * xi + 2.f * xi * om);
            const float den = d_k + (d_k1 + d_k - 2.f) * xi * om;
            const float yv  = ch_k + num / (den + 1e-8f);
            const float dv  = h_k * h_k * (d_k1 * xi * xi + 2.f * xi * om + d_k * om * om)
                              / (den * den * w_k + 1e-8f) + 1e-8f;

            float v = __logf(dv);
            v += __shfl_xor(v, 1);
            v += __shfl_xor(v, 2);
            v += __shfl_xor(v, 4);
            ldacc += v;

            outY[g * 64 + 2 * t]     = xp[g * 64 + 2 * t];
            outY[g * 64 + 2 * t + 1] = yv;
        }
        __syncthreads();
    }

    if (tid < 256 && tl == 0) outLD[row0 + r] = ldacc;
}

extern "C" void kernel_launch(void* const* d_in, const int* in_sizes, int n_in,
                              void* d_out, int out_size, void* d_ws, size_t ws_size,
                              hipStream_t stream) {
    (void)in_sizes; (void)n_in; (void)out_size; (void)ws_size;
    const float* x   = (const float*)d_in[0];
    const float* ctx = (const float*)d_in[1];
    const float* W1  = (const float*)d_in[2];
    const float* b1  = (const float*)d_in[3];
    const float* W2  = (const float*)d_in[4];
    const float* b2  = (const float*)d_in[5];
    const float* W3  = (const float*)d_in[6];
    const float* b3  = (const float*)d_in[7];

    _Float16* base = (_Float16*)d_ws;
    _Float16* W1Thi = base;                    // 512x128   = 65536
    _Float16* W1Tlo = base + 65536;
    _Float16* W2Thi = base + 131072;           // 512x512   = 262144
    _Float16* W2Tlo = base + 393216;
    _Float16* W3Thi = base + 655360;           // 1504x512  = 770048
    _Float16* W3Tlo = base + 1425408;

    nscl_prep_frag<<<(512 * 128 + 255) / 256, 256, 0, stream>>>(W1, W1Thi, W1Tlo, 128, 512);
    nscl_prep_frag<<<(512 * 512 + 255) / 256, 256, 0, stream>>>(W2, W2Thi, W2Tlo, 512, 512);
    nscl_prep_frag<<<(512 * 1504 + 255) / 256, 256, 0, stream>>>(W3, W3Thi, W3Tlo, 512, 1504);

    float* outY  = (float*)d_out;
    float* outLD = outY + 65536 * 64;

    nscl_fused<<<NBLOCKS, 1024, 0, stream>>>(x, ctx, b1, b2, b3,
                                             W1Thi, W1Tlo, W2Thi, W2Tlo, W3Thi, W3Tlo,
                                             outY, outLD);
}

// Round 10
// 1162.374 us; speedup vs baseline: 1.5205x; 1.3959x over previous
//
#include <hip/hip_runtime.h>

// ---------------------------------------------------------------------------
// NeuralSplineCouplingLayer fused kernel (MI355X / gfx950) — round 10
// R4-R9 established: for 1024-thread blocks the backend pins VGPR=64 and any
// structure beyond R4's spills (1.4-3.3GB scratch). amdgpu_waves_per_eu did
// NOT override it (R9). R3 showed 512-thread blocks get VGPR=128.
// R10 = R7's verified-numerics body (absmax 0.0625) at 512 threads / 8 waves:
//   * frag-linear A+B (conflict-free b128), dual-acc split-fp16
//   * gemm12: wave owns 4 N-tiles sequentially; gemm3: 3 tiles/wave
//   * array-free spline; LDS 147KB -> 1 block/CU, 2 waves/SIMD
// ---------------------------------------------------------------------------

typedef _Float16 v8h __attribute__((ext_vector_type(8)));
typedef float v4f __attribute__((ext_vector_type(4)));

#define ROWS_PER_BLOCK 32
#define NBLOCKS 2048
#define NWAVES 8

// LDS layout (bytes). A-planes fragment-linear: plane[mt][ks][lane][8] fp16.
//   sInpHi [0,      8192)   2 x 4  x 64 x 8
//   sInpLo [8192,  16384)
//   sH1Hi  [16384, 49152)   2 x 16 x 64 x 8
//   sH1Lo  [49152, 81920)
//   sH2Hi  [81920, 114688)
//   sH2Lo  [114688,147456)
//   sRaw   [0,     49664)   32 x 388 f32 — overlays inp+h1 (dead in phase 3)
#define SMEM_BYTES 147456
#define S_INPLO 8192
#define S_H1HI  16384
#define S_H1LO  49152
#define S_H2HI  81920
#define S_H2LO  114688
#define RAW_STRIDE 388

#define LO_SCALE 2048.f
#define LO_INV   (1.f / 2048.f)

__device__ __forceinline__ void split2(float x, _Float16& hi, _Float16& lo) {
    _Float16 h = (_Float16)x;
    hi = h;
    lo = (_Float16)((x - (float)h) * LO_SCALE);
}
__device__ __forceinline__ float silu_f(float v) {
    return v / (1.f + __expf(-v));
}
__device__ __forceinline__ float softplus_f(float v) {
    return v > 15.f ? v : __logf(1.f + __expf(v));
}

// --- prep: W (K x N) f32 -> fragment-contiguous fp16 hi/lo -----------------
// Bfrag[j][ks][lane][e]: col n = j*16+(lane&15), k = ks*32+((lane>>4)<<3)+e.
__global__ void nscl_prep_frag(const float* __restrict__ src,
                               _Float16* __restrict__ hi, _Float16* __restrict__ lo,
                               int K, int N) {
    int idx = blockIdx.x * blockDim.x + threadIdx.x;
    if (idx >= N * K) return;
    const int e    = idx & 7;
    const int lane = (idx >> 3) & 63;
    const int rem  = idx >> 9;
    const int KS   = K >> 5;
    const int ks   = rem % KS;
    const int j    = rem / KS;
    const int n = j * 16 + (lane & 15);
    const int k = ks * 32 + ((lane >> 4) << 3) + e;
    split2(src[k * N + n], hi[idx], lo[idx]);
}

// --- GEMM1/2: wave owns 4 N-tiles, processed SEQUENTIALLY ------------------
template<int KS>
__device__ __forceinline__ void gemm12(const _Float16* __restrict__ sAhi,
                                       const _Float16* __restrict__ sAlo,
                                       const _Float16* __restrict__ Bhi,
                                       const _Float16* __restrict__ Blo,
                                       const float* __restrict__ bias,
                                       _Float16* __restrict__ sOutHi,
                                       _Float16* __restrict__ sOutLo,
                                       int wave, int lane) {
    const int r2b = (lane >> 4) * 4;
    #pragma unroll 1
    for (int jj = 0; jj < 4; ++jj) {
        const int j = wave * 4 + jj;
        v4f m0 = {0,0,0,0}, m1 = {0,0,0,0};
        v4f c0 = {0,0,0,0}, c1 = {0,0,0,0};
        #pragma unroll
        for (int ks = 0; ks < KS; ++ks) {
            const int ab = (ks * 64 + lane) * 8;
            v8h a0h = *(const v8h*)(sAhi + ab);
            v8h a0l = *(const v8h*)(sAlo + ab);
            v8h a1h = *(const v8h*)(sAhi + KS * 512 + ab);
            v8h a1l = *(const v8h*)(sAlo + KS * 512 + ab);
            const int bo = ((j * KS + ks) * 64 + lane) * 8;
            v8h bh = *(const v8h*)(Bhi + bo);
            v8h bl = *(const v8h*)(Blo + bo);
            m0 = __builtin_amdgcn_mfma_f32_16x16x32_f16(a0h, bh, m0, 0, 0, 0);
            m1 = __builtin_amdgcn_mfma_f32_16x16x32_f16(a1h, bh, m1, 0, 0, 0);
            c0 = __builtin_amdgcn_mfma_f32_16x16x32_f16(a0h, bl, c0, 0, 0, 0);
            c0 = __builtin_amdgcn_mfma_f32_16x16x32_f16(a0l, bh, c0, 0, 0, 0);
            c1 = __builtin_amdgcn_mfma_f32_16x16x32_f16(a1h, bl, c1, 0, 0, 0);
            c1 = __builtin_amdgcn_mfma_f32_16x16x32_f16(a1l, bh, c1, 0, 0, 0);
        }
        // epilogue -> fragment layout (out K-dim = 512, KSout = 16)
        const int C   = j * 16 + (lane & 15);
        const int ks2 = C >> 5, g2 = (C >> 3) & 3, e2 = C & 7;
        const float bv = bias[C];
        #pragma unroll
        for (int rr = 0; rr < 4; ++rr) {
            float v0 = silu_f(m0[rr] + c0[rr] * LO_INV + bv);
            float v1 = silu_f(m1[rr] + c1[rr] * LO_INV + bv);
            const int off0 = ((0 * 16 + ks2) * 64 + g2 * 16 + r2b + rr) * 8 + e2;
            const int off1 = ((1 * 16 + ks2) * 64 + g2 * 16 + r2b + rr) * 8 + e2;
            split2(v0, sOutHi[off0], sOutLo[off0]);
            split2(v1, sOutHi[off1], sOutLo[off1]);
        }
    }
}

// --- GEMM3 chunk: 24 tiles from t0, one tile per iter, named accs ----------
__device__ __forceinline__ void gemm3(const _Float16* __restrict__ sAhi,
                                      const _Float16* __restrict__ sAlo,
                                      const _Float16* __restrict__ Bhi,
                                      const _Float16* __restrict__ Blo,
                                      const float* __restrict__ b3,
                                      float* __restrict__ sRaw,
                                      int t0, int wave, int lane) {
    #pragma unroll 1
    for (int tt = wave; tt < 24; tt += NWAVES) {
        const int jt = t0 + tt;
        v4f m0 = {0,0,0,0}, m1 = {0,0,0,0};
        v4f cc0 = {0,0,0,0}, cc1 = {0,0,0,0};
        #pragma unroll
        for (int ks = 0; ks < 16; ++ks) {
            const int ab = (ks * 64 + lane) * 8;
            v8h a0h = *(const v8h*)(sAhi + ab);
            v8h a0l = *(const v8h*)(sAlo + ab);
            v8h a1h = *(const v8h*)(sAhi + 8192 + ab);
            v8h a1l = *(const v8h*)(sAlo + 8192 + ab);
            const int bo = ((jt * 16 + ks) * 64 + lane) * 8;
            v8h bh = *(const v8h*)(Bhi + bo);
            v8h bl = *(const v8h*)(Blo + bo);
            m0  = __builtin_amdgcn_mfma_f32_16x16x32_f16(a0h, bh, m0, 0, 0, 0);
            m1  = __builtin_amdgcn_mfma_f32_16x16x32_f16(a1h, bh, m1, 0, 0, 0);
            cc0 = __builtin_amdgcn_mfma_f32_16x16x32_f16(a0h, bl, cc0, 0, 0, 0);
            cc0 = __builtin_amdgcn_mfma_f32_16x16x32_f16(a0l, bh, cc0, 0, 0, 0);
            cc1 = __builtin_amdgcn_mfma_f32_16x16x32_f16(a1h, bl, cc1, 0, 0, 0);
            cc1 = __builtin_amdgcn_mfma_f32_16x16x32_f16(a1l, bh, cc1, 0, 0, 0);
        }
        const int lr   = lane & 15;
        const int lcol = tt * 16 + lr;
        const float bv = b3[jt * 16 + lr];
        const int r2b  = (lane >> 4) * 4;
        #pragma unroll
        for (int rr = 0; rr < 4; ++rr) {
            sRaw[(r2b + rr) * RAW_STRIDE + lcol]      = m0[rr] + cc0[rr] * LO_INV + bv;
            sRaw[(16 + r2b + rr) * RAW_STRIDE + lcol] = m1[rr] + cc1[rr] * LO_INV + bv;
        }
    }
}

__global__ __launch_bounds__(512, 2)
void nscl_fused(const float* __restrict__ xp, const float* __restrict__ ctxp,
                const float* __restrict__ b1, const float* __restrict__ b2,
                const float* __restrict__ b3,
                const _Float16* __restrict__ W1Thi, const _Float16* __restrict__ W1Tlo,
                const _Float16* __restrict__ W2Thi, const _Float16* __restrict__ W2Tlo,
                const _Float16* __restrict__ W3Thi, const _Float16* __restrict__ W3Tlo,
                float* __restrict__ outY, float* __restrict__ outLD) {
    __shared__ __align__(16) char smem[SMEM_BYTES];
    _Float16* sInpHi = (_Float16*)smem;
    _Float16* sInpLo = (_Float16*)(smem + S_INPLO);
    _Float16* sH1Hi  = (_Float16*)(smem + S_H1HI);
    _Float16* sH1Lo  = (_Float16*)(smem + S_H1LO);
    _Float16* sH2Hi  = (_Float16*)(smem + S_H2HI);
    _Float16* sH2Lo  = (_Float16*)(smem + S_H2LO);
    float*    sRaw   = (float*)smem;               // overlay (phase 3)

    const int tid  = threadIdx.x;
    const int lane = tid & 63;
    const int wave = tid >> 6;
    const int row0 = blockIdx.x * ROWS_PER_BLOCK;

    // ---- stage masked input directly into fragment layout (array-free) ----
    {
        const int mt = tid >> 8;
        const int l  = tid & 63;
        const int row = mt * 16 + (l & 15);
        const int c0  = ((tid >> 6) & 3) * 32 + ((l >> 4) << 3);
        const int g   = row0 + row;
        v8h hi8, lo8;
        #pragma unroll
        for (int e = 0; e < 8; ++e) {
            float v;
            if (c0 < 64) v = ((c0 + e) & 1) ? 0.f : xp[g * 64 + c0 + e];
            else         v = ctxp[g * 64 + c0 - 64 + e];
            _Float16 h = (_Float16)v;
            hi8[e] = h;
            lo8[e] = (_Float16)((v - (float)h) * LO_SCALE);
        }
        *(v8h*)(sInpHi + tid * 8) = hi8;
        *(v8h*)(sInpLo + tid * 8) = lo8;
    }
    __syncthreads();

    gemm12<4>(sInpHi, sInpLo, W1Thi, W1Tlo, b1, sH1Hi, sH1Lo, wave, lane);
    __syncthreads();
    gemm12<16>(sH1Hi, sH1Lo, W2Thi, W2Tlo, b2, sH2Hi, sH2Lo, wave, lane);
    __syncthreads();

    // ---- GEMM3 + spline, 4 chunks of 8 transforms --------------------------
    const float TB = 5.0f;
    float ldacc = 0.f;
    const int r  = (tid < 256) ? (tid >> 3) : 0;
    const int tl = tid & 7;

    #pragma unroll 1
    for (int ch = 0; ch < 4; ++ch) {
        const int t0 = (ch * 47) >> 1;           // 0, 23, 47, 70
        gemm3(sH2Hi, sH2Lo, W3Thi, W3Tlo, b3, sRaw, t0, wave, lane);
        __syncthreads();

        if (tid < 256) {
            const int t = ch * 8 + tl;
            const int g = row0 + r;
            const float* pr = sRaw + r * RAW_STRIDE + ((ch & 1) ? 8 : 0) + tl * 47;

            // pass 1: maxes
            float mw = -1e30f, mh = -1e30f;
            #pragma unroll
            for (int i = 0; i < 16; ++i) {
                mw = fmaxf(mw, pr[i]);
                mh = fmaxf(mh, pr[16 + i]);
            }
            // pass 2: softmax sums
            float sw = 0.f, sh = 0.f;
            #pragma unroll
            for (int i = 0; i < 16; ++i) {
                sw += __expf(pr[i] - mw);
                sh += __expf(pr[16 + i] - mh);
            }
            const float scw = 10.f / sw;
            const float sch = 10.f / sh;

            const float xt = xp[g * 64 + 2 * t + 1];
            const float xc = fminf(fmaxf(xt, -TB + 1e-6f), TB - 1e-6f);

            // pass 3: bin count (sequential cumsum, recomputed exp)
            float cum = -TB; int cnt = 0;
            #pragma unroll
            for (int i = 0; i < 16; ++i) {
                cum += __expf(pr[i] - mw) * scw;
                cnt += (cum < xc) ? 1 : 0;
            }
            const int bin = cnt > 15 ? 15 : cnt;

            // pass 4: gather at bin (recomputed exp, predicated select)
            float w_k = 0.f, cw_k = 0.f, h_k = 0.f, ch_k = 0.f;
            float cw = -TB, chh = -TB;
            #pragma unroll
            for (int i = 0; i < 16; ++i) {
                const float wi = __expf(pr[i] - mw) * scw;
                const float hi = __expf(pr[16 + i] - mh) * sch;
                if (i == bin) { w_k = wi; cw_k = cw; h_k = hi; ch_k = chh; }
                cw += wi; chh += hi;
            }

            const float d_k  = (bin == 0)  ? 1.f : softplus_f(pr[31 + bin]);
            const float d_k1 = (bin == 15) ? 1.f : softplus_f(pr[32 + bin]);

            float xi = (xc - cw_k) / w_k;
            xi = fminf(fmaxf(xi, 0.f), 1.f);
            const float om = 1.f - xi;
            const float num = h_k * (d_k * xi * xi + 2.f * xi * om);
            const float den = d_k + (d_k1 + d_k - 2.f) * xi * om;
            const float yv  = ch_k + num / (den + 1e-8f);
            const float dv  = h_k * h_k * (d_k1 * xi * xi + 2.f * xi * om + d_k * om * om)
                              / (den * den * w_k + 1e-8f) + 1e-8f;

            float v = __logf(dv);
            v += __shfl_xor(v, 1);
            v += __shfl_xor(v, 2);
            v += __shfl_xor(v, 4);
            ldacc += v;

            outY[g * 64 + 2 * t]     = xp[g * 64 + 2 * t];
            outY[g * 64 + 2 * t + 1] = yv;
        }
        __syncthreads();
    }

    if (tid < 256 && tl == 0) outLD[row0 + r] = ldacc;
}

extern "C" void kernel_launch(void* const* d_in, const int* in_sizes, int n_in,
                              void* d_out, int out_size, void* d_ws, size_t ws_size,
                              hipStream_t stream) {
    (void)in_sizes; (void)n_in; (void)out_size; (void)ws_size;
    const float* x   = (const float*)d_in[0];
    const float* ctx = (const float*)d_in[1];
    const float* W1  = (const float*)d_in[2];
    const float* b1  = (const float*)d_in[3];
    const float* W2  = (const float*)d_in[4];
    const float* b2  = (const float*)d_in[5];
    const float* W3  = (const float*)d_in[6];
    const float* b3  = (const float*)d_in[7];

    _Float16* base = (_Float16*)d_ws;
    _Float16* W1Thi = base;                    // 512x128   = 65536
    _Float16* W1Tlo = base + 65536;
    _Float16* W2Thi = base + 131072;           // 512x512   = 262144
    _Float16* W2Tlo = base + 393216;
    _Float16* W3Thi = base + 655360;           // 1504x512  = 770048
    _Float16* W3Tlo = base + 1425408;

    nscl_prep_frag<<<(512 * 128 + 255) / 256, 256, 0, stream>>>(W1, W1Thi, W1Tlo, 128, 512);
    nscl_prep_frag<<<(512 * 512 + 255) / 256, 256, 0, stream>>>(W2, W2Thi, W2Tlo, 512, 512);
    nscl_prep_frag<<<(512 * 1504 + 255) / 256, 256, 0, stream>>>(W3, W3Thi, W3Tlo, 512, 1504);

    float* outY  = (float*)d_out;
    float* outLD = outY + 65536 * 64;

    nscl_fused<<<NBLOCKS, 512, 0, stream>>>(x, ctx, b1, b2, b3,
                                            W1Thi, W1Tlo, W2Thi, W2Tlo, W3Thi, W3Tlo,
                                            outY, outLD);
}

// Round 11
// 765.091 us; speedup vs baseline: 2.3101x; 1.5193x over previous
//
#include <hip/hip_runtime.h>

// ---------------------------------------------------------------------------
// NeuralSplineCouplingLayer fused kernel (MI355X / gfx950) — round 11
// R4 (713us) is the ONLY clean-codegen kernel measured (WRITE=outY exactly);
// every structural variant since (R5-R10) triggered scratch spills regardless
// of VGPR budget. R11 = R4 source with ONE arithmetic-only change:
//   A-planes at power-of-2 stride (128/512 elems) with 16B-chunk XOR swizzle
//   (chunk ^= row&7) on every A access — kills R4's 6.3e7 bank conflicts
//   (rows at 1KB stride all alias the same banks) without touching loop
//   structure, accumulators, staging, spline, or launch config.
// ---------------------------------------------------------------------------

typedef _Float16 v8h __attribute__((ext_vector_type(8)));
typedef float v4f __attribute__((ext_vector_type(4)));

#define ROWS_PER_BLOCK 32
#define NBLOCKS (65536 / ROWS_PER_BLOCK)
#define NWAVES 16

// LDS layout (bytes):
//   sInpHi [0,      8192)   32 x 128 fp16 (swizzled)
//   sInpLo [8192,  16384)
//   sH1Hi  [16384, 49152)   32 x 512 fp16 (swizzled)
//   sH1Lo  [49152, 81920)
//   sH2Hi  [81920, 114688)
//   sH2Lo  [114688,147456)
//   sRaw   [0,     49664)   32 x 388 f32 — overlays inp+h1 (dead in phase 3)
#define SMEM_BYTES 147456
#define S_INPLO 8192
#define S_H1HI  16384
#define S_H1LO  49152
#define S_H2HI  81920
#define S_H2LO  114688
#define RAW_STRIDE 388

#define LO_SCALE 2048.f
#define LO_INV   (1.f / 2048.f)

__device__ __forceinline__ void split2(float x, _Float16& hi, _Float16& lo) {
    _Float16 h = (_Float16)x;
    hi = h;
    lo = (_Float16)((x - (float)h) * LO_SCALE);
}
__device__ __forceinline__ float silu_f(float v) {
    return v / (1.f + __expf(-v));
}
__device__ __forceinline__ float softplus_f(float v) {
    return v > 15.f ? v : __logf(1.f + __expf(v));
}

// --- prep: W (K x N) f32 -> fragment-contiguous fp16 hi/lo -----------------
// Bfrag[j][ks][lane][e]: col n = j*16+(lane&15), k = ks*32+((lane>>4)<<3)+e.
__global__ void nscl_prep_frag(const float* __restrict__ src,
                               _Float16* __restrict__ hi, _Float16* __restrict__ lo,
                               int K, int N) {
    int idx = blockIdx.x * blockDim.x + threadIdx.x;
    if (idx >= N * K) return;
    const int e    = idx & 7;
    const int lane = (idx >> 3) & 63;
    const int rem  = idx >> 9;
    const int KS   = K >> 5;
    const int ks   = rem % KS;
    const int j    = rem / KS;
    const int n = j * 16 + (lane & 15);
    const int k = ks * 32 + ((lane >> 4) << 3) + e;
    split2(src[k * N + n], hi[idx], lo[idx]);
}

// --- split GEMM phase: sOut = act(sA @ W + b), swizzled A ------------------
// 16 waves; each wave owns one 32x32 output patch (2 M-tiles x 2 N-tiles).
template<int KD, int SA, int NPAIRS, bool DOSILU>
__device__ __forceinline__ void gemm_phase(const _Float16* __restrict__ sAhi,
                                           const _Float16* __restrict__ sAlo,
                                           const _Float16* __restrict__ Bhi,
                                           const _Float16* __restrict__ Blo,
                                           const float* __restrict__ bias,
                                           _Float16* __restrict__ sOutHi,
                                           _Float16* __restrict__ sOutLo,
                                           int wave, int lane) {
    constexpr int KS = KD / 32;
    const int lr  = lane & 15;
    const int lkb = (lane >> 4) << 3;
    const int rb  = (lane >> 4) << 2;
    const int lx  = lr & 7;                 // row-XOR key (rows lr and 16+lr share it)

    for (int p = wave; p < NPAIRS; p += NWAVES) {
        const int j0 = p * 2;
        v4f m00 = {0,0,0,0}, m10 = {0,0,0,0}, m01 = {0,0,0,0}, m11 = {0,0,0,0};
        v4f c00 = {0,0,0,0}, c10 = {0,0,0,0}, c01 = {0,0,0,0}, c11 = {0,0,0,0};
        #pragma unroll
        for (int ks = 0; ks < KS; ++ks) {
            const int k0 = ks * 32 + lkb;
            const int ax = (((k0 >> 3) ^ lx) << 3);     // swizzled elem offset
            v8h a0h = *(const v8h*)(sAhi + lr * SA + ax);
            v8h a0l = *(const v8h*)(sAlo + lr * SA + ax);
            v8h a1h = *(const v8h*)(sAhi + (16 + lr) * SA + ax);
            v8h a1l = *(const v8h*)(sAlo + (16 + lr) * SA + ax);
            const int bo0 = ((j0 * KS + ks) * 64 + lane) * 8;
            const int bo1 = (((j0 + 1) * KS + ks) * 64 + lane) * 8;
            v8h b0h = *(const v8h*)(Bhi + bo0);
            v8h b0l = *(const v8h*)(Blo + bo0);
            v8h b1h = *(const v8h*)(Bhi + bo1);
            v8h b1l = *(const v8h*)(Blo + bo1);
            m00 = __builtin_amdgcn_mfma_f32_16x16x32_f16(a0h, b0h, m00, 0, 0, 0);
            m10 = __builtin_amdgcn_mfma_f32_16x16x32_f16(a1h, b0h, m10, 0, 0, 0);
            m01 = __builtin_amdgcn_mfma_f32_16x16x32_f16(a0h, b1h, m01, 0, 0, 0);
            m11 = __builtin_amdgcn_mfma_f32_16x16x32_f16(a1h, b1h, m11, 0, 0, 0);
            c00 = __builtin_amdgcn_mfma_f32_16x16x32_f16(a0h, b0l, c00, 0, 0, 0);
            c00 = __builtin_amdgcn_mfma_f32_16x16x32_f16(a0l, b0h, c00, 0, 0, 0);
            c10 = __builtin_amdgcn_mfma_f32_16x16x32_f16(a1h, b0l, c10, 0, 0, 0);
            c10 = __builtin_amdgcn_mfma_f32_16x16x32_f16(a1l, b0h, c10, 0, 0, 0);
            c01 = __builtin_amdgcn_mfma_f32_16x16x32_f16(a0h, b1l, c01, 0, 0, 0);
            c01 = __builtin_amdgcn_mfma_f32_16x16x32_f16(a0l, b1h, c01, 0, 0, 0);
            c11 = __builtin_amdgcn_mfma_f32_16x16x32_f16(a1h, b1l, c11, 0, 0, 0);
            c11 = __builtin_amdgcn_mfma_f32_16x16x32_f16(a1l, b1h, c11, 0, 0, 0);
        }
        #pragma unroll
        for (int jj = 0; jj < 2; ++jj) {
            const int col  = (j0 + jj) * 16 + lr;
            const int colc = col >> 3, ce = col & 7;
            const float bv = bias[col];
            const v4f mm0 = jj ? m01 : m00;
            const v4f mm1 = jj ? m11 : m10;
            const v4f cc0 = jj ? c01 : c00;
            const v4f cc1 = jj ? c11 : c10;
            #pragma unroll
            for (int r = 0; r < 4; ++r) {
                float v0 = mm0[r] + cc0[r] * LO_INV + bv;
                float v1 = mm1[r] + cc1[r] * LO_INV + bv;
                if (DOSILU) { v0 = silu_f(v0); v1 = silu_f(v1); }
                const int row = rb + r;
                const int cc  = (((colc ^ (row & 7)) << 3) | ce);   // row&7 == (16+row)&7
                split2(v0, sOutHi[row * 512 + cc],        sOutLo[row * 512 + cc]);
                split2(v1, sOutHi[(16 + row) * 512 + cc], sOutLo[(16 + row) * 512 + cc]);
            }
        }
    }
}

// --- GEMM3 chunk (split): 24 tiles starting at tile t0, fp32 out -----------
__device__ __forceinline__ void gemm3_chunk(const _Float16* __restrict__ sH2Hi,
                                            const _Float16* __restrict__ sH2Lo,
                                            const _Float16* __restrict__ W3hi,
                                            const _Float16* __restrict__ W3lo,
                                            const float* __restrict__ b3,
                                            float* __restrict__ sRaw,
                                            int t0, int wave, int lane) {
    const int lr  = lane & 15;
    const int lkb = (lane >> 4) << 3;
    const int rb  = (lane >> 4) << 2;
    const int lx  = lr & 7;

    for (int tt = wave; tt < 24; tt += NWAVES) {
        const int jt = t0 + tt;
        v4f m0 = {0,0,0,0}, m1 = {0,0,0,0};
        v4f cc0 = {0,0,0,0}, cc1 = {0,0,0,0};
        #pragma unroll
        for (int ks = 0; ks < 16; ++ks) {
            const int k0 = ks * 32 + lkb;
            const int ax = (((k0 >> 3) ^ lx) << 3);
            v8h a0h = *(const v8h*)(sH2Hi + lr * 512 + ax);
            v8h a0l = *(const v8h*)(sH2Lo + lr * 512 + ax);
            v8h a1h = *(const v8h*)(sH2Hi + (16 + lr) * 512 + ax);
            v8h a1l = *(const v8h*)(sH2Lo + (16 + lr) * 512 + ax);
            const int bo = ((jt * 16 + ks) * 64 + lane) * 8;
            v8h bh = *(const v8h*)(W3hi + bo);
            v8h bl = *(const v8h*)(W3lo + bo);
            m0  = __builtin_amdgcn_mfma_f32_16x16x32_f16(a0h, bh, m0, 0, 0, 0);
            m1  = __builtin_amdgcn_mfma_f32_16x16x32_f16(a1h, bh, m1, 0, 0, 0);
            cc0 = __builtin_amdgcn_mfma_f32_16x16x32_f16(a0h, bl, cc0, 0, 0, 0);
            cc0 = __builtin_amdgcn_mfma_f32_16x16x32_f16(a0l, bh, cc0, 0, 0, 0);
            cc1 = __builtin_amdgcn_mfma_f32_16x16x32_f16(a1h, bl, cc1, 0, 0, 0);
            cc1 = __builtin_amdgcn_mfma_f32_16x16x32_f16(a1l, bh, cc1, 0, 0, 0);
        }
        const int col  = jt * 16 + lr;      // < 1504 always (94 tiles exactly)
        const int lcol = tt * 16 + lr;
        const float bv = b3[col];
        #pragma unroll
        for (int r = 0; r < 4; ++r) {
            sRaw[(rb + r) * RAW_STRIDE + lcol]      = m0[r] + cc0[r] * LO_INV + bv;
            sRaw[(16 + rb + r) * RAW_STRIDE + lcol] = m1[r] + cc1[r] * LO_INV + bv;
        }
    }
}

__global__ __launch_bounds__(1024, 4)
void nscl_fused(const float* __restrict__ xp, const float* __restrict__ ctxp,
                const float* __restrict__ b1, const float* __restrict__ b2,
                const float* __restrict__ b3,
                const _Float16* __restrict__ W1Thi, const _Float16* __restrict__ W1Tlo,
                const _Float16* __restrict__ W2Thi, const _Float16* __restrict__ W2Tlo,
                const _Float16* __restrict__ W3Thi, const _Float16* __restrict__ W3Tlo,
                float* __restrict__ outY, float* __restrict__ outLD) {
    __shared__ __align__(16) char smem[SMEM_BYTES];
    _Float16* sInpHi = (_Float16*)smem;
    _Float16* sInpLo = (_Float16*)(smem + S_INPLO);
    _Float16* sH1Hi  = (_Float16*)(smem + S_H1HI);
    _Float16* sH1Lo  = (_Float16*)(smem + S_H1LO);
    _Float16* sH2Hi  = (_Float16*)(smem + S_H2HI);
    _Float16* sH2Lo  = (_Float16*)(smem + S_H2LO);
    float*    sRaw   = (float*)smem;               // overlay (phase 3)

    const int tid  = threadIdx.x;
    const int lane = tid & 63;
    const int wave = tid >> 6;
    const int row0 = blockIdx.x * ROWS_PER_BLOCK;

    // ---- stage masked input [x_masked | context] split, swizzled ----------
    for (int idx = tid; idx < ROWS_PER_BLOCK * 128; idx += 1024) {
        int r = idx >> 7, c = idx & 127;
        float v;
        if (c < 64) v = (c & 1) ? 0.f : xp[(row0 + r) * 64 + c];
        else        v = ctxp[(row0 + r) * 64 + (c - 64)];
        const int cc = (((c >> 3) ^ (r & 7)) << 3) | (c & 7);
        split2(v, sInpHi[r * 128 + cc], sInpLo[r * 128 + cc]);
    }
    __syncthreads();

    gemm_phase<128, 128, 16, true>(sInpHi, sInpLo, W1Thi, W1Tlo, b1,
                                   sH1Hi, sH1Lo, wave, lane);
    __syncthreads();
    gemm_phase<512, 512, 16, true>(sH1Hi, sH1Lo, W2Thi, W2Tlo, b2,
                                   sH2Hi, sH2Lo, wave, lane);
    __syncthreads();

    // ---- GEMM3 + spline, 4 chunks of 8 transforms (24 tile-aligned tiles) --
    const float TB = 5.0f;
    float ldacc = 0.f;
    const int r  = (tid < 256) ? (tid >> 3) : 0;
    const int tl = tid & 7;
    const int t0s[4] = {0, 23, 47, 70};   // tile-aligned chunk starts

    #pragma unroll 1
    for (int ch = 0; ch < 4; ++ch) {
        gemm3_chunk(sH2Hi, sH2Lo, W3Thi, W3Tlo, b3, sRaw, t0s[ch], wave, lane);
        __syncthreads();

        if (tid < 256) {
            const int t = ch * 8 + tl;
            const int g = row0 + r;
            // local col of transform t within chunk: 47*tl - 16*t0 + 376*ch
            const float* pr = sRaw + r * RAW_STRIDE + ((ch & 1) ? 8 : 0) + tl * 47;

            float mw = -1e30f, mh = -1e30f;
            #pragma unroll
            for (int i = 0; i < 16; ++i) {
                mw = fmaxf(mw, pr[i]);
                mh = fmaxf(mh, pr[16 + i]);
            }
            float wv[16], hv[16];
            float sw = 0.f, sh = 0.f;
            #pragma unroll
            for (int i = 0; i < 16; ++i) {
                wv[i] = __expf(pr[i] - mw);       sw += wv[i];
                hv[i] = __expf(pr[16 + i] - mh);  sh += hv[i];
            }
            const float scw = 10.f / sw;
            const float sch = 10.f / sh;

            const float xt = xp[g * 64 + 2 * t + 1];
            const float xc = fminf(fmaxf(xt, -TB + 1e-6f), TB - 1e-6f);

            float cum = -TB; int cnt = 0;
            #pragma unroll
            for (int i = 0; i < 16; ++i) {
                cum += wv[i] * scw;
                cnt += (cum < xc) ? 1 : 0;
            }
            const int bin = cnt > 15 ? 15 : cnt;

            float w_k = 0.f, cw_k = 0.f, h_k = 0.f, ch_k = 0.f;
            float cw = -TB, chh = -TB;
            #pragma unroll
            for (int i = 0; i < 16; ++i) {
                const float wi = wv[i] * scw;
                const float hi = hv[i] * sch;
                if (i == bin) { w_k = wi; cw_k = cw; h_k = hi; ch_k = chh; }
                cw += wi; chh += hi;
            }

            const float d_k  = (bin == 0)  ? 1.f : softplus_f(pr[31 + bin]);
            const float d_k1 = (bin == 15) ? 1.f : softplus_f(pr[32 + bin]);

            float xi = (xc - cw_k) / w_k;
            xi = fminf(fmaxf(xi, 0.f), 1.f);
            const float om = 1.f - xi;
            const float num = h_k * (d_k * xi * xi + 2.f * xi * om);
            const float den = d_k + (d_k1 + d_k - 2.f) * xi * om;
            const float yv  = ch_k + num / (den + 1e-8f);
            const float dv  = h_k * h_k * (d_k1 * xi * xi + 2.f * xi * om + d_k * om * om)
                              / (den * den * w_k + 1e-8f) + 1e-8f;

            float v = __logf(dv);
            v += __shfl_xor(v, 1);
            v += __shfl_xor(v, 2);
            v += __shfl_xor(v, 4);
            ldacc += v;

            outY[g * 64 + 2 * t]     = xp[g * 64 + 2 * t];
            outY[g * 64 + 2 * t + 1] = yv;
        }
        __syncthreads();
    }

    if (tid < 256 && tl == 0) outLD[row0 + r] = ldacc;
}

extern "C" void kernel_launch(void* const* d_in, const int* in_sizes, int n_in,
                              void* d_out, int out_size, void* d_ws, size_t ws_size,
                              hipStream_t stream) {
    (void)in_sizes; (void)n_in; (void)out_size; (void)ws_size;
    const float* x   = (const float*)d_in[0];
    const float* ctx = (const float*)d_in[1];
    const float* W1  = (const float*)d_in[2];
    const float* b1  = (const float*)d_in[3];
    const float* W2  = (const float*)d_in[4];
    const float* b2  = (const float*)d_in[5];
    const float* W3  = (const float*)d_in[6];
    const float* b3  = (const float*)d_in[7];

    _Float16* base = (_Float16*)d_ws;
    _Float16* W1Thi = base;                    // 512x128   = 65536
    _Float16* W1Tlo = base + 65536;
    _Float16* W2Thi = base + 131072;           // 512x512   = 262144
    _Float16* W2Tlo = base + 393216;
    _Float16* W3Thi = base + 655360;           // 1504x512  = 770048
    _Float16* W3Tlo = base + 1425408;

    nscl_prep_frag<<<(512 * 128 + 255) / 256, 256, 0, stream>>>(W1, W1Thi, W1Tlo, 128, 512);
    nscl_prep_frag<<<(512 * 512 + 255) / 256, 256, 0, stream>>>(W2, W2Thi, W2Tlo, 512, 512);
    nscl_prep_frag<<<(512 * 1504 + 255) / 256, 256, 0, stream>>>(W3, W3Thi, W3Tlo, 512, 1504);

    float* outY  = (float*)d_out;
    float* outLD = outY + 65536 * 64;

    nscl_fused<<<NBLOCKS, 1024, 0, stream>>>(x, ctx, b1, b2, b3,
                                             W1Thi, W1Tlo, W2Thi, W2Tlo, W3Thi, W3Tlo,
                                             outY, outLD);
}

// Round 12
// 640.073 us; speedup vs baseline: 2.7613x; 1.1953x over previous
//
#include <hip/hip_runtime.h>

// ---------------------------------------------------------------------------
// NeuralSplineCouplingLayer fused kernel (MI355X / gfx950) — round 12
// R11 lesson: XOR-swizzle at 1KB row stride does NOT fix b128 conflicts
// (count identical to R4's 6.32e7) — only FRAGMENT-LINEAR A (wave reads one
// contiguous 1KB span) measured conflict-free (R5/R6: 6.6e6). But R5-R10's
// loop restructures all spilled. R12 = R4's exact loop/accumulator/spline
// structure with ONLY the A addressing changed to frag-linear:
//   * A-read: base + (ks*64+lane)*8, ks/mt offsets fold into ds_read imms
//     (less addressing pressure than lr*SA+k0)
//   * staging + GEMM1/2 epilogues scatter-write frag layout (scalar stores)
// Launch config, B path, spline, chunking: R4 verbatim.
// ---------------------------------------------------------------------------

typedef _Float16 v8h __attribute__((ext_vector_type(8)));
typedef float v4f __attribute__((ext_vector_type(4)));

#define ROWS_PER_BLOCK 32
#define NBLOCKS (65536 / ROWS_PER_BLOCK)
#define NWAVES 16

// LDS layout (bytes). A-planes fragment-linear: plane[mt][ks][lane][8] fp16.
//   sInpHi [0,      8192)   2 x 4  x 64 x 8
//   sInpLo [8192,  16384)
//   sH1Hi  [16384, 49152)   2 x 16 x 64 x 8
//   sH1Lo  [49152, 81920)
//   sH2Hi  [81920, 114688)
//   sH2Lo  [114688,147456)
//   sRaw   [0,     49664)   32 x 388 f32 — overlays inp+h1 (dead in phase 3)
#define SMEM_BYTES 147456
#define S_INPLO 8192
#define S_H1HI  16384
#define S_H1LO  49152
#define S_H2HI  81920
#define S_H2LO  114688
#define RAW_STRIDE 388

#define LO_SCALE 2048.f
#define LO_INV   (1.f / 2048.f)

__device__ __forceinline__ void split2(float x, _Float16& hi, _Float16& lo) {
    _Float16 h = (_Float16)x;
    hi = h;
    lo = (_Float16)((x - (float)h) * LO_SCALE);
}
__device__ __forceinline__ float silu_f(float v) {
    return v / (1.f + __expf(-v));
}
__device__ __forceinline__ float softplus_f(float v) {
    return v > 15.f ? v : __logf(1.f + __expf(v));
}

// --- prep: W (K x N) f32 -> fragment-contiguous fp16 hi/lo -----------------
// Bfrag[j][ks][lane][e]: col n = j*16+(lane&15), k = ks*32+((lane>>4)<<3)+e.
__global__ void nscl_prep_frag(const float* __restrict__ src,
                               _Float16* __restrict__ hi, _Float16* __restrict__ lo,
                               int K, int N) {
    int idx = blockIdx.x * blockDim.x + threadIdx.x;
    if (idx >= N * K) return;
    const int e    = idx & 7;
    const int lane = (idx >> 3) & 63;
    const int rem  = idx >> 9;
    const int KS   = K >> 5;
    const int ks   = rem % KS;
    const int j    = rem / KS;
    const int n = j * 16 + (lane & 15);
    const int k = ks * 32 + ((lane >> 4) << 3) + e;
    split2(src[k * N + n], hi[idx], lo[idx]);
}

// --- split GEMM phase: sOut = act(sA @ W + b); A frag-linear ---------------
// 16 waves; each wave owns one 32x32 output patch (2 M-tiles x 2 N-tiles).
template<int KS, int NPAIRS, bool DOSILU>
__device__ __forceinline__ void gemm_phase(const _Float16* __restrict__ sAhi,
                                           const _Float16* __restrict__ sAlo,
                                           const _Float16* __restrict__ Bhi,
                                           const _Float16* __restrict__ Blo,
                                           const float* __restrict__ bias,
                                           _Float16* __restrict__ sOutHi,
                                           _Float16* __restrict__ sOutLo,
                                           int wave, int lane) {
    const int lr = lane & 15;
    const int rb = (lane >> 4) << 2;

    for (int p = wave; p < NPAIRS; p += NWAVES) {
        const int j0 = p * 2;
        v4f m00 = {0,0,0,0}, m10 = {0,0,0,0}, m01 = {0,0,0,0}, m11 = {0,0,0,0};
        v4f c00 = {0,0,0,0}, c10 = {0,0,0,0}, c01 = {0,0,0,0}, c11 = {0,0,0,0};
        #pragma unroll
        for (int ks = 0; ks < KS; ++ks) {
            const int ab = (ks * 64 + lane) * 8;
            v8h a0h = *(const v8h*)(sAhi + ab);
            v8h a0l = *(const v8h*)(sAlo + ab);
            v8h a1h = *(const v8h*)(sAhi + KS * 512 + ab);
            v8h a1l = *(const v8h*)(sAlo + KS * 512 + ab);
            const int bo0 = ((j0 * KS + ks) * 64 + lane) * 8;
            const int bo1 = (((j0 + 1) * KS + ks) * 64 + lane) * 8;
            v8h b0h = *(const v8h*)(Bhi + bo0);
            v8h b0l = *(const v8h*)(Blo + bo0);
            v8h b1h = *(const v8h*)(Bhi + bo1);
            v8h b1l = *(const v8h*)(Blo + bo1);
            m00 = __builtin_amdgcn_mfma_f32_16x16x32_f16(a0h, b0h, m00, 0, 0, 0);
            m10 = __builtin_amdgcn_mfma_f32_16x16x32_f16(a1h, b0h, m10, 0, 0, 0);
            m01 = __builtin_amdgcn_mfma_f32_16x16x32_f16(a0h, b1h, m01, 0, 0, 0);
            m11 = __builtin_amdgcn_mfma_f32_16x16x32_f16(a1h, b1h, m11, 0, 0, 0);
            c00 = __builtin_amdgcn_mfma_f32_16x16x32_f16(a0h, b0l, c00, 0, 0, 0);
            c00 = __builtin_amdgcn_mfma_f32_16x16x32_f16(a0l, b0h, c00, 0, 0, 0);
            c10 = __builtin_amdgcn_mfma_f32_16x16x32_f16(a1h, b0l, c10, 0, 0, 0);
            c10 = __builtin_amdgcn_mfma_f32_16x16x32_f16(a1l, b0h, c10, 0, 0, 0);
            c01 = __builtin_amdgcn_mfma_f32_16x16x32_f16(a0h, b1l, c01, 0, 0, 0);
            c01 = __builtin_amdgcn_mfma_f32_16x16x32_f16(a0l, b1h, c01, 0, 0, 0);
            c11 = __builtin_amdgcn_mfma_f32_16x16x32_f16(a1h, b1l, c11, 0, 0, 0);
            c11 = __builtin_amdgcn_mfma_f32_16x16x32_f16(a1l, b1h, c11, 0, 0, 0);
        }
        #pragma unroll
        for (int jj = 0; jj < 2; ++jj) {
            const int C   = (j0 + jj) * 16 + lr;
            const int ks2 = C >> 5, g2 = (C >> 3) & 3, e2 = C & 7;
            const float bv = bias[C];
            const v4f mm0 = jj ? m01 : m00;
            const v4f mm1 = jj ? m11 : m10;
            const v4f cc0 = jj ? c01 : c00;
            const v4f cc1 = jj ? c11 : c10;
            #pragma unroll
            for (int r = 0; r < 4; ++r) {
                float v0 = mm0[r] + cc0[r] * LO_INV + bv;
                float v1 = mm1[r] + cc1[r] * LO_INV + bv;
                if (DOSILU) { v0 = silu_f(v0); v1 = silu_f(v1); }
                const int off0 = (ks2 * 64 + g2 * 16 + rb + r) * 8 + e2;
                const int off1 = ((16 + ks2) * 64 + g2 * 16 + rb + r) * 8 + e2;
                split2(v0, sOutHi[off0], sOutLo[off0]);
                split2(v1, sOutHi[off1], sOutLo[off1]);
            }
        }
    }
}

// --- GEMM3 chunk (split): 24 tiles starting at tile t0, fp32 out -----------
__device__ __forceinline__ void gemm3_chunk(const _Float16* __restrict__ sH2Hi,
                                            const _Float16* __restrict__ sH2Lo,
                                            const _Float16* __restrict__ W3hi,
                                            const _Float16* __restrict__ W3lo,
                                            const float* __restrict__ b3,
                                            float* __restrict__ sRaw,
                                            int t0, int wave, int lane) {
    const int lr = lane & 15;
    const int rb = (lane >> 4) << 2;

    for (int tt = wave; tt < 24; tt += NWAVES) {
        const int jt = t0 + tt;
        v4f m0 = {0,0,0,0}, m1 = {0,0,0,0};
        v4f cc0 = {0,0,0,0}, cc1 = {0,0,0,0};
        #pragma unroll
        for (int ks = 0; ks < 16; ++ks) {
            const int ab = (ks * 64 + lane) * 8;
            v8h a0h = *(const v8h*)(sH2Hi + ab);
            v8h a0l = *(const v8h*)(sH2Lo + ab);
            v8h a1h = *(const v8h*)(sH2Hi + 8192 + ab);
            v8h a1l = *(const v8h*)(sH2Lo + 8192 + ab);
            const int bo = ((jt * 16 + ks) * 64 + lane) * 8;
            v8h bh = *(const v8h*)(W3hi + bo);
            v8h bl = *(const v8h*)(W3lo + bo);
            m0  = __builtin_amdgcn_mfma_f32_16x16x32_f16(a0h, bh, m0, 0, 0, 0);
            m1  = __builtin_amdgcn_mfma_f32_16x16x32_f16(a1h, bh, m1, 0, 0, 0);
            cc0 = __builtin_amdgcn_mfma_f32_16x16x32_f16(a0h, bl, cc0, 0, 0, 0);
            cc0 = __builtin_amdgcn_mfma_f32_16x16x32_f16(a0l, bh, cc0, 0, 0, 0);
            cc1 = __builtin_amdgcn_mfma_f32_16x16x32_f16(a1h, bl, cc1, 0, 0, 0);
            cc1 = __builtin_amdgcn_mfma_f32_16x16x32_f16(a1l, bh, cc1, 0, 0, 0);
        }
        const int col  = jt * 16 + lr;      // < 1504 always (94 tiles exactly)
        const int lcol = tt * 16 + lr;
        const float bv = b3[col];
        #pragma unroll
        for (int r = 0; r < 4; ++r) {
            sRaw[(rb + r) * RAW_STRIDE + lcol]      = m0[r] + cc0[r] * LO_INV + bv;
            sRaw[(16 + rb + r) * RAW_STRIDE + lcol] = m1[r] + cc1[r] * LO_INV + bv;
        }
    }
}

__global__ __launch_bounds__(1024, 4)
void nscl_fused(const float* __restrict__ xp, const float* __restrict__ ctxp,
                const float* __restrict__ b1, const float* __restrict__ b2,
                const float* __restrict__ b3,
                const _Float16* __restrict__ W1Thi, const _Float16* __restrict__ W1Tlo,
                const _Float16* __restrict__ W2Thi, const _Float16* __restrict__ W2Tlo,
                const _Float16* __restrict__ W3Thi, const _Float16* __restrict__ W3Tlo,
                float* __restrict__ outY, float* __restrict__ outLD) {
    __shared__ __align__(16) char smem[SMEM_BYTES];
    _Float16* sInpHi = (_Float16*)smem;
    _Float16* sInpLo = (_Float16*)(smem + S_INPLO);
    _Float16* sH1Hi  = (_Float16*)(smem + S_H1HI);
    _Float16* sH1Lo  = (_Float16*)(smem + S_H1LO);
    _Float16* sH2Hi  = (_Float16*)(smem + S_H2HI);
    _Float16* sH2Lo  = (_Float16*)(smem + S_H2LO);
    float*    sRaw   = (float*)smem;               // overlay (phase 3)

    const int tid  = threadIdx.x;
    const int lane = tid & 63;
    const int wave = tid >> 6;
    const int row0 = blockIdx.x * ROWS_PER_BLOCK;

    // ---- stage masked input into frag layout (scalar, R4-style loop) -------
    for (int idx = tid; idx < ROWS_PER_BLOCK * 128; idx += 1024) {
        const int e  = idx & 7;
        const int l  = (idx >> 3) & 63;
        const int ks = (idx >> 9) & 3;
        const int mt = idx >> 11;
        const int row = mt * 16 + (l & 15);
        const int c   = ks * 32 + ((l >> 4) << 3) + e;
        float v;
        if (c < 64) v = (c & 1) ? 0.f : xp[(row0 + row) * 64 + c];
        else        v = ctxp[(row0 + row) * 64 + (c - 64)];
        split2(v, sInpHi[idx], sInpLo[idx]);
    }
    __syncthreads();

    gemm_phase<4, 16, true>(sInpHi, sInpLo, W1Thi, W1Tlo, b1,
                            sH1Hi, sH1Lo, wave, lane);
    __syncthreads();
    gemm_phase<16, 16, true>(sH1Hi, sH1Lo, W2Thi, W2Tlo, b2,
                             sH2Hi, sH2Lo, wave, lane);
    __syncthreads();

    // ---- GEMM3 + spline, 4 chunks of 8 transforms (24 tile-aligned tiles) --
    const float TB = 5.0f;
    float ldacc = 0.f;
    const int r  = (tid < 256) ? (tid >> 3) : 0;
    const int tl = tid & 7;
    const int t0s[4] = {0, 23, 47, 70};   // tile-aligned chunk starts

    #pragma unroll 1
    for (int ch = 0; ch < 4; ++ch) {
        gemm3_chunk(sH2Hi, sH2Lo, W3Thi, W3Tlo, b3, sRaw, t0s[ch], wave, lane);
        __syncthreads();

        if (tid < 256) {
            const int t = ch * 8 + tl;
            const int g = row0 + r;
            // local col of transform t within chunk: 376*ch + 47*tl - 16*t0
            const float* pr = sRaw + r * RAW_STRIDE + ((ch & 1) ? 8 : 0) + tl * 47;

            float mw = -1e30f, mh = -1e30f;
            #pragma unroll
            for (int i = 0; i < 16; ++i) {
                mw = fmaxf(mw, pr[i]);
                mh = fmaxf(mh, pr[16 + i]);
            }
            float wv[16], hv[16];
            float sw = 0.f, sh = 0.f;
            #pragma unroll
            for (int i = 0; i < 16; ++i) {
                wv[i] = __expf(pr[i] - mw);       sw += wv[i];
                hv[i] = __expf(pr[16 + i] - mh);  sh += hv[i];
            }
            const float scw = 10.f / sw;
            const float sch = 10.f / sh;

            const float xt = xp[g * 64 + 2 * t + 1];
            const float xc = fminf(fmaxf(xt, -TB + 1e-6f), TB - 1e-6f);

            float cum = -TB; int cnt = 0;
            #pragma unroll
            for (int i = 0; i < 16; ++i) {
                cum += wv[i] * scw;
                cnt += (cum < xc) ? 1 : 0;
            }
            const int bin = cnt > 15 ? 15 : cnt;

            float w_k = 0.f, cw_k = 0.f, h_k = 0.f, ch_k = 0.f;
            float cw = -TB, chh = -TB;
            #pragma unroll
            for (int i = 0; i < 16; ++i) {
                const float wi = wv[i] * scw;
                const float hi = hv[i] * sch;
                if (i == bin) { w_k = wi; cw_k = cw; h_k = hi; ch_k = chh; }
                cw += wi; chh += hi;
            }

            const float d_k  = (bin == 0)  ? 1.f : softplus_f(pr[31 + bin]);
            const float d_k1 = (bin == 15) ? 1.f : softplus_f(pr[32 + bin]);

            float xi = (xc - cw_k) / w_k;
            xi = fminf(fmaxf(xi, 0.f), 1.f);
            const float om = 1.f - xi;
            const float num = h_k * (d_k * xi * xi + 2.f * xi * om);
            const float den = d_k + (d_k1 + d_k - 2.f) * xi * om;
            const float yv  = ch_k + num / (den + 1e-8f);
            const float dv  = h_k * h_k * (d_k1 * xi * xi + 2.f * xi * om + d_k * om * om)
                              / (den * den * w_k + 1e-8f) + 1e-8f;

            float v = __logf(dv);
            v += __shfl_xor(v, 1);
            v += __shfl_xor(v, 2);
            v += __shfl_xor(v, 4);
            ldacc += v;

            outY[g * 64 + 2 * t]     = xp[g * 64 + 2 * t];
            outY[g * 64 + 2 * t + 1] = yv;
        }
        __syncthreads();
    }

    if (tid < 256 && tl == 0) outLD[row0 + r] = ldacc;
}

extern "C" void kernel_launch(void* const* d_in, const int* in_sizes, int n_in,
                              void* d_out, int out_size, void* d_ws, size_t ws_size,
                              hipStream_t stream) {
    (void)in_sizes; (void)n_in; (void)out_size; (void)ws_size;
    const float* x   = (const float*)d_in[0];
    const float* ctx = (const float*)d_in[1];
    const float* W1  = (const float*)d_in[2];
    const float* b1  = (const float*)d_in[3];
    const float* W2  = (const float*)d_in[4];
    const float* b2  = (const float*)d_in[5];
    const float* W3  = (const float*)d_in[6];
    const float* b3  = (const float*)d_in[7];

    _Float16* base = (_Float16*)d_ws;
    _Float16* W1Thi = base;                    // 512x128   = 65536
    _Float16* W1Tlo = base + 65536;
    _Float16* W2Thi = base + 131072;           // 512x512   = 262144
    _Float16* W2Tlo = base + 393216;
    _Float16* W3Thi = base + 655360;           // 1504x512  = 770048
    _Float16* W3Tlo = base + 1425408;

    nscl_prep_frag<<<(512 * 128 + 255) / 256, 256, 0, stream>>>(W1, W1Thi, W1Tlo, 128, 512);
    nscl_prep_frag<<<(512 * 512 + 255) / 256, 256, 0, stream>>>(W2, W2Thi, W2Tlo, 512, 512);
    nscl_prep_frag<<<(512 * 1504 + 255) / 256, 256, 0, stream>>>(W3, W3Thi, W3Tlo, 512, 1504);

    float* outY  = (float*)d_out;
    float* outLD = outY + 65536 * 64;

    nscl_fused<<<NBLOCKS, 1024, 0, stream>>>(x, ctx, b1, b2, b3,
                                             W1Thi, W1Tlo, W2Thi, W2Tlo, W3Thi, W3Tlo,
                                             outY, outLD);
}